// Round 3
// baseline (1559.272 us; speedup 1.0000x reference)
//
#include <hip/hip_runtime.h>

typedef unsigned short u16;
typedef unsigned int u32;

#define NTOK 144
#define CDIM 192
#define NHEADS 6
#define HDIM 32
#define NWIN 64
#define NB 30
#define NBLK (NB * NWIN)
#define TABLE_N 3312
#define SCALE 0.17677669529663687f

typedef __bf16 bf16x8 __attribute__((ext_vector_type(8)));
typedef u16 u16x8 __attribute__((ext_vector_type(8)));
typedef float f32x4 __attribute__((ext_vector_type(4)));

__device__ __forceinline__ float bf2f(u16 u) {
    union { u32 i; float f; } v; v.i = ((u32)u) << 16; return v.f;
}
__device__ __forceinline__ u16 f2bf(float f) {
    union { float f; u32 i; } v; v.f = f;
    u32 r = v.i + 0x7FFFu + ((v.i >> 16) & 1u);   // RNE
    return (u16)(r >> 16);
}

// -------- dtype-robust accessors (fm==1: raw buffers are fp32) --------
__device__ __forceinline__ bf16x8 ld_frag(const void* base, size_t idx, int fm) {
    if (!fm) return *(const bf16x8*)((const u16*)base + idx);
    const float* pf = (const float*)base;
    u16x8 t;
#pragma unroll
    for (int j = 0; j < 8; ++j) t[j] = f2bf(pf[idx + j]);
    union { u16x8 u; bf16x8 b; } cv; cv.u = t; return cv.b;
}
__device__ __forceinline__ float ld_s(const void* base, size_t idx, int fm) {
    return fm ? ((const float*)base)[idx] : bf2f(((const u16*)base)[idx]);
}
__device__ __forceinline__ void st_s(void* base, size_t idx, float v, int fm) {
    if (fm) ((float*)base)[idx] = v; else ((u16*)base)[idx] = f2bf(v);
}
__device__ __forceinline__ bf16x8 zero_frag() {
    union { u16x8 u; bf16x8 b; } cv;
#pragma unroll
    for (int j = 0; j < 8; ++j) cv.u[j] = 0;
    return cv.b;
}
// x A-fragment loader (16B worth of bf16; converts when fm)
__device__ __forceinline__ bf16x8 ld_x_frag(const void* x, size_t rowbase, int off, int fm) {
    if (!fm) return *(const bf16x8*)((const u16*)x + rowbase + off);
    const float* xs = (const float*)x + rowbase + off;
    const float4 a0 = *(const float4*)xs;
    const float4 a1 = *(const float4*)(xs + 4);
    union { u16x8 u; bf16x8 b; } cv;
    cv.u[0] = f2bf(a0.x); cv.u[1] = f2bf(a0.y); cv.u[2] = f2bf(a0.z); cv.u[3] = f2bf(a0.w);
    cv.u[4] = f2bf(a1.x); cv.u[5] = f2bf(a1.y); cv.u[6] = f2bf(a1.z); cv.u[7] = f2bf(a1.w);
    return cv.b;
}

// -------- detector: bf16 vs fp32 input encoding --------
__global__ void detect_mode(const u16* __restrict__ w, int* __restrict__ flag) {
    __shared__ int cnt;
    if (threadIdx.x == 0) cnt = 0;
    __syncthreads();
    int h = 0;
    for (int i = threadIdx.x; i < 4096; i += 256) {
        int e = (w[i] >> 7) & 0xFF;
        if (e >= 0x8E) h++;
    }
    atomicAdd(&cnt, h);
    __syncthreads();
    if (threadIdx.x == 0) flag[0] = (cnt > 64) ? 1 : 0;
}

// -------- prologue: bias_g[w*6+h][n*144+m] via LDS-staged table slice --------
// One block per w: stage table[:, w, :] (3312x6 bf16 = 39.7KB) in LDS, then
// coalesced gather-writes. Replaces 8.5M scattered 4B global reads (~280us).
__global__ void bias_gather2(const void* __restrict__ table, const int* __restrict__ pos,
                             u16* __restrict__ bias_g, const int* __restrict__ mode) {
    __shared__ u16 smT[TABLE_N * NHEADS];
    const int fm = mode[0];
    const int w = blockIdx.x;
    for (int i = threadIdx.x; i < TABLE_N * NHEADS; i += 256) {
        int t = i / NHEADS, h = i - t * NHEADS;
        size_t j = (size_t)t * (NWIN * NHEADS) + w * NHEADS + h;
        smT[i] = fm ? f2bf(((const float*)table)[j]) : ((const u16*)table)[j];
    }
    __syncthreads();
    for (int i = threadIdx.x; i < NTOK * NTOK; i += 256) {
        int base = pos[i] * NHEADS;
#pragma unroll
        for (int h = 0; h < NHEADS; ++h)
            bias_g[((size_t)(w * NHEADS + h)) * (NTOK * NTOK) + i] = smT[base + h];
    }
}

// -------- prologue: canonical bf16 weights in workspace (one-time) --------
__global__ void wconv(const void* __restrict__ qkv_w, const void* __restrict__ qkv_b,
                      const void* __restrict__ proj_w, const void* __restrict__ proj_b,
                      u16* __restrict__ qkvw_c, u16* __restrict__ projw_c,
                      u16* __restrict__ qkvb_c, u16* __restrict__ projb_c,
                      const int* __restrict__ mode) {
    const int fm = mode[0];
    const int gid = blockIdx.x * blockDim.x + threadIdx.x;
    const int np  = gridDim.x * blockDim.x;
    const int NQW = 3 * CDIM * CDIM, NPW = CDIM * CDIM;
    if (fm) {
        const float* a = (const float*)qkv_w;
        const float* b = (const float*)proj_w;
        const float* c = (const float*)qkv_b;
        const float* d = (const float*)proj_b;
        for (int i = gid; i < NQW; i += np) qkvw_c[i] = f2bf(a[i]);
        for (int i = gid; i < NPW; i += np) projw_c[i] = f2bf(b[i]);
        for (int i = gid; i < 3 * CDIM; i += np) qkvb_c[i] = f2bf(c[i]);
        for (int i = gid; i < CDIM; i += np) projb_c[i] = f2bf(d[i]);
    } else {
        const u16* a = (const u16*)qkv_w;
        const u16* b = (const u16*)proj_w;
        const u16* c = (const u16*)qkv_b;
        const u16* d = (const u16*)proj_b;
        for (int i = gid; i < NQW; i += np) qkvw_c[i] = a[i];
        for (int i = gid; i < NPW; i += np) projw_c[i] = b[i];
        for (int i = gid; i < 3 * CDIM; i += np) qkvb_c[i] = c[i];
        for (int i = gid; i < CDIM; i += np) projb_c[i] = d[i];
    }
}

// =================== split-path kernel 1: fused qkv + attention ===================
// 512 threads (8 waves), 2 blocks/CU target. Wave wv owns M-tile wv; wave 0 also
// owns tile 8. O_h written to global o_ws (bf16 [NBLK*144][192]); proj in kernel 2.
// LDS (u16): Q[144][40]@0, K[144][40]@5760, P[144][152]@11520, vT[32][152]@33408
// Strides: 40u16=20dw, 152u16=76dw==12 mod 32 -> 8-bank row spread (2-way, free).
// K=160 pad eliminated: kt=4 MFMA uses lq-masked A-frag (k=144..159 contributes 0).
#define AQ_OFF  0
#define AK_OFF  5760
#define AQK_STR 40
#define AP_OFF  11520
#define AP_STR  152
#define AVT_OFF 33408
#define AVT_STR 152
#define ASM_TOT 38272    // u16 units = 76,544 B  (2 blocks = 153 KB <= 160 KB)

__global__ __launch_bounds__(512, 4)
void attn_qkv(const void* __restrict__ x,
              const u16* __restrict__ qkvw_c, const u16* __restrict__ qkvb_c,
              const u16* __restrict__ bias_g, u16* __restrict__ o_ws,
              const int* __restrict__ mode) {
    __shared__ __align__(16) u16 sm[ASM_TOT];

    const int fm   = mode[0];
    const int tid  = threadIdx.x;
    const int wv   = tid >> 6;       // 0..7
    const int lane = tid & 63;
    const int l15  = lane & 15;
    const int lq   = lane >> 4;      // 0..3

    // XCD-chunked swizzle + window-major remap (bias_g/weights L2-local per XCD)
    const int blk   = blockIdx.x;                       // 0..1919
    const int virt  = (blk & 7) * (NBLK / 8) + (blk >> 3);
    const int w     = virt / NB;                        // 0..63
    const int bwlin = (virt % NB) * NWIN + w;           // linear (b,w) index into x/o_ws

    const size_t xrowA = ((size_t)bwlin * NTOK + wv * 16 + l15) * CDIM;
    const size_t xrow8 = ((size_t)bwlin * NTOK + 128 + l15) * CDIM;

    // x A-fragments for own tile -> registers once (reused by all 6 heads)
    bf16x8 xfrag[6];
#pragma unroll
    for (int kt = 0; kt < 6; ++kt) xfrag[kt] = ld_x_frag(x, xrowA, kt * 32 + lq * 8, fm);

    const f32x4 fzero = {0.f, 0.f, 0.f, 0.f};

    for (int h = 0; h < NHEADS; ++h) {
        const int hoff = h * HDIM;

        // ---- t1: qkv_h = x @ Wh^T (M=144,N=96,K=192); A regs, B global (L2-hot) ----
        f32x4 accA[6], accB[6];
#pragma unroll
        for (int nt = 0; nt < 6; ++nt) { accA[nt] = fzero; accB[nt] = fzero; }
        int wrow[6];
#pragma unroll
        for (int nt = 0; nt < 6; ++nt) {
            int c = nt * 16 + l15, s = c >> 5, d = c & 31;
            wrow[nt] = (s * CDIM + hoff + d) * CDIM;
        }
#pragma unroll
        for (int kt = 0; kt < 6; ++kt) {
            bf16x8 a8;
            if (wv == 0) a8 = ld_x_frag(x, xrow8, kt * 32 + lq * 8, fm);
#pragma unroll
            for (int nt = 0; nt < 6; ++nt) {
                bf16x8 bb = *(const bf16x8*)&qkvw_c[(size_t)wrow[nt] + kt * 32 + lq * 8];
                accA[nt] = __builtin_amdgcn_mfma_f32_16x16x32_bf16(xfrag[kt], bb, accA[nt], 0, 0, 0);
                if (wv == 0)
                    accB[nt] = __builtin_amdgcn_mfma_f32_16x16x32_bf16(a8, bb, accB[nt], 0, 0, 0);
            }
        }

        // scatter q (scaled) / k / v^T as bf16 for tile T
        auto scatter = [&](const f32x4* acc, int T) {
#pragma unroll
            for (int nt = 0; nt < 6; ++nt) {
                int col = nt * 16 + l15;         // 0..95
                int s = col >> 5, d = col & 31;
                float bias = bf2f(qkvb_c[s * CDIM + hoff + d]);
#pragma unroll
                for (int r = 0; r < 4; ++r) {
                    int row = T * 16 + lq * 4 + r;
                    float v = acc[nt][r] + bias;
                    if (s == 0)      sm[AQ_OFF + row * AQK_STR + d] = f2bf(v * SCALE);
                    else if (s == 1) sm[AK_OFF + row * AQK_STR + d] = f2bf(v);
                    else             sm[AVT_OFF + d * AVT_STR + row] = f2bf(v);
                }
            }
        };
        scatter(accA, wv);
        if (wv == 0) scatter(accB, 8);
        __syncthreads();                              // B1 (q/k/vT visible)

        // ---- t2: S = q@k^T + bias; softmax in regs; P write (tile T) ----
        auto t2_tile = [&](int T) {
            f32x4 sacc[9];
            bf16x8 a = *(const bf16x8*)&sm[AQ_OFF + (T * 16 + l15) * AQK_STR + lq * 8];
#pragma unroll
            for (int nt = 0; nt < 9; ++nt) {
                bf16x8 bb = *(const bf16x8*)&sm[AK_OFF + (nt * 16 + l15) * AQK_STR + lq * 8];
                sacc[nt] = __builtin_amdgcn_mfma_f32_16x16x32_bf16(a, bb, fzero, 0, 0, 0);
            }
            const u16* bg = bias_g + (size_t)(w * NHEADS + h) * (NTOK * NTOK);
#pragma unroll
            for (int nt = 0; nt < 9; ++nt) {
                int col = nt * 16 + l15;
#pragma unroll
                for (int r = 0; r < 4; ++r)
                    sacc[nt][r] += bf2f(bg[(T * 16 + lq * 4 + r) * NTOK + col]);
            }
#pragma unroll
            for (int r = 0; r < 4; ++r) {
                float m = -1e30f;
                for (int nt = 0; nt < 9; ++nt) m = fmaxf(m, sacc[nt][r]);
                for (int d = 1; d < 16; d <<= 1) m = fmaxf(m, __shfl_xor(m, d, 64));
                float s = 0.f;
                for (int nt = 0; nt < 9; ++nt) {
                    float e = __expf(sacc[nt][r] - m);
                    sacc[nt][r] = e; s += e;
                }
                for (int d = 1; d < 16; d <<= 1) s += __shfl_xor(s, d, 64);
                float inv = 1.0f / s;
                for (int nt = 0; nt < 9; ++nt) sacc[nt][r] *= inv;
            }
#pragma unroll
            for (int r = 0; r < 4; ++r) {
                int row = T * 16 + lq * 4 + r;
#pragma unroll
                for (int nt = 0; nt < 9; ++nt)
                    sm[AP_OFF + row * AP_STR + nt * 16 + l15] = f2bf(sacc[nt][r]);
            }
        };
        t2_tile(wv);
        if (wv == 0) t2_tile(8);
        __syncthreads();                              // B2 (P ready; q/k dead)

        // ---- t3: O_h = P @ v (M=144,N=32,K=144 via masked kt=4); O -> global ----
        auto t3_tile = [&](int T) {
            f32x4 pv[2] = {fzero, fzero};
#pragma unroll
            for (int kt = 0; kt < 4; ++kt) {
                bf16x8 a = *(const bf16x8*)&sm[AP_OFF + (T * 16 + l15) * AP_STR + kt * 32 + lq * 8];
#pragma unroll
                for (int dt = 0; dt < 2; ++dt) {
                    bf16x8 bb = *(const bf16x8*)&sm[AVT_OFF + (dt * 16 + l15) * AVT_STR + kt * 32 + lq * 8];
                    pv[dt] = __builtin_amdgcn_mfma_f32_16x16x32_bf16(a, bb, pv[dt], 0, 0, 0);
                }
            }
            // kt=4: real k = 128..143 only (lq 0,1); lq 2,3 masked to zero A-frag
            bf16x8 a4 = zero_frag();
            if (lq < 2)
                a4 = *(const bf16x8*)&sm[AP_OFF + (T * 16 + l15) * AP_STR + 128 + lq * 8];
#pragma unroll
            for (int dt = 0; dt < 2; ++dt) {
                bf16x8 bb = *(const bf16x8*)&sm[AVT_OFF + (dt * 16 + l15) * AVT_STR + 128 + (lq & 1) * 8];
                pv[dt] = __builtin_amdgcn_mfma_f32_16x16x32_bf16(a4, bb, pv[dt], 0, 0, 0);
            }
            u16* op = o_ws + ((size_t)bwlin * NTOK + T * 16 + lq * 4) * CDIM + hoff;
#pragma unroll
            for (int dt = 0; dt < 2; ++dt)
#pragma unroll
                for (int r = 0; r < 4; ++r)
                    op[r * CDIM + dt * 16 + l15] = f2bf(pv[dt][r]);
        };
        t3_tile(wv);
        if (wv == 0) t3_tile(8);
        __syncthreads();                              // B3 (P/vT dead; next head safe)
    }
}

// =================== split-path kernel 2: output projection GEMM ===================
// out = O @ proj_w^T + b. 256 threads (4 waves), no LDS, 4 blocks/CU target.
__global__ __launch_bounds__(256, 4)
void proj_gemm(const u16* __restrict__ o_ws, const u16* __restrict__ projw_c,
               const u16* __restrict__ projb_c, void* __restrict__ out,
               const int* __restrict__ mode) {
    const int fm   = mode[0];
    const int tid  = threadIdx.x;
    const int wv   = tid >> 6;
    const int lane = tid & 63;
    const int l15  = lane & 15;
    const int lq   = lane >> 4;
    const int tile = blockIdx.x * 4 + wv;             // 0..17279
    const size_t rb = (size_t)tile * 16;

    const f32x4 fzero = {0.f, 0.f, 0.f, 0.f};
    bf16x8 a[6];
#pragma unroll
    for (int kt = 0; kt < 6; ++kt)
        a[kt] = *(const bf16x8*)&o_ws[(rb + l15) * CDIM + kt * 32 + lq * 8];

    f32x4 acc[12];
#pragma unroll
    for (int nt = 0; nt < 12; ++nt) acc[nt] = fzero;
#pragma unroll
    for (int kt = 0; kt < 6; ++kt) {
#pragma unroll
        for (int nt = 0; nt < 12; ++nt) {
            bf16x8 bb = *(const bf16x8*)&projw_c[(size_t)(nt * 16 + l15) * CDIM + kt * 32 + lq * 8];
            acc[nt] = __builtin_amdgcn_mfma_f32_16x16x32_bf16(a[kt], bb, acc[nt], 0, 0, 0);
        }
    }
#pragma unroll
    for (int nt = 0; nt < 12; ++nt) {
        int col = nt * 16 + l15;
        float pb = bf2f(projb_c[col]);
#pragma unroll
        for (int r = 0; r < 4; ++r)
            st_s(out, (rb + lq * 4 + r) * CDIM + col, acc[nt][r] + pb, fm);
    }
}

// =================== fallback: R2 monolithic fused kernel ===================
#define Q_OFF  0
#define K_OFF  5760
#define QK_STR 40
#define P_OFF  11520
#define P_STR  168
#define VT_OFF 35712
#define VT_STR 168
#define OA_OFF 41088
#define OA_STR 200
#define SM_TOT 69888

template<int FASTW>
__global__ __launch_bounds__(576, 3)
void earth_attn_fused(const void* __restrict__ x, const void* __restrict__ qkv_w,
                const void* __restrict__ qkv_b, const void* __restrict__ proj_w,
                const void* __restrict__ proj_b, const void* __restrict__ bias_table,
                const int* __restrict__ pos_index,
                const u16* __restrict__ qkvw_c, const u16* __restrict__ projw_c,
                const u16* __restrict__ qkvb_c, const u16* __restrict__ projb_c,
                const u16* __restrict__ bias_g, int use_bias_g,
                void* __restrict__ out, const int* __restrict__ mode) {
    __shared__ __align__(16) u16 sm[SM_TOT];

    const int fm   = mode[0];
    const int tid  = threadIdx.x;
    const int wv   = tid >> 6;
    const int lane = tid & 63;
    const int l15  = lane & 15;
    const int lq   = lane >> 4;

    const int blk   = blockIdx.x;
    const int virt  = (blk & 7) * (NBLK / 8) + (blk >> 3);
    const int w     = virt / NB;
    const int bwlin = (virt % NB) * NWIN + w;

    {
        uint4 z; z.x = z.y = z.z = z.w = 0u;
        for (int i = tid; i < (32 * VT_STR) / 8; i += 576) *(uint4*)&sm[VT_OFF + i * 8] = z;
    }

    bf16x8 xfrag[6];
    {
        const size_t xrow = ((size_t)bwlin * NTOK + wv * 16 + l15) * CDIM;
#pragma unroll
        for (int kt = 0; kt < 6; ++kt) xfrag[kt] = ld_x_frag(x, xrow, kt * 32 + lq * 8, fm);
    }
    __syncthreads();

    const f32x4 fzero = {0.f, 0.f, 0.f, 0.f};

    for (int h = 0; h < NHEADS; ++h) {
        const int hoff = h * HDIM;

        float bsv[9][4];
        if (FASTW || use_bias_g) {
            const u16* bg = bias_g + (size_t)(w * NHEADS + h) * (NTOK * NTOK);
#pragma unroll
            for (int nt = 0; nt < 9; ++nt) {
                int col = nt * 16 + l15;
#pragma unroll
                for (int r = 0; r < 4; ++r)
                    bsv[nt][r] = bf2f(bg[(wv * 16 + lq * 4 + r) * NTOK + col]);
            }
        } else {
#pragma unroll
            for (int nt = 0; nt < 9; ++nt) {
                int col = nt * 16 + l15;
#pragma unroll
                for (int r = 0; r < 4; ++r) {
                    int idx = pos_index[(wv * 16 + lq * 4 + r) * NTOK + col];
                    bsv[nt][r] = ld_s(bias_table, ((size_t)idx * NWIN + w) * NHEADS + h, fm);
                }
            }
        }

        {
            f32x4 acc[6];
            for (int nt = 0; nt < 6; ++nt) acc[nt] = fzero;
            int wrow[6];
#pragma unroll
            for (int nt = 0; nt < 6; ++nt) {
                int c = nt * 16 + l15, s = c >> 5, d = c & 31;
                wrow[nt] = (s * CDIM + hoff + d) * CDIM;
            }
#pragma unroll
            for (int kt = 0; kt < 6; ++kt) {
#pragma unroll
                for (int nt = 0; nt < 6; ++nt) {
                    bf16x8 bb = FASTW
                        ? *(const bf16x8*)&qkvw_c[(size_t)wrow[nt] + kt * 32 + lq * 8]
                        : ld_frag(qkv_w, (size_t)wrow[nt] + kt * 32 + lq * 8, fm);
                    acc[nt] = __builtin_amdgcn_mfma_f32_16x16x32_bf16(xfrag[kt], bb, acc[nt], 0, 0, 0);
                }
            }
#pragma unroll
            for (int nt = 0; nt < 6; ++nt) {
                int col = nt * 16 + l15;
                int s = col >> 5, d = col & 31;
                float bias = FASTW ? bf2f(qkvb_c[s * CDIM + hoff + d])
                                   : ld_s(qkv_b, s * CDIM + hoff + d, fm);
#pragma unroll
                for (int r = 0; r < 4; ++r) {
                    int row = wv * 16 + lq * 4 + r;
                    float v = acc[nt][r] + bias;
                    if (s == 0)      sm[Q_OFF + row * QK_STR + d] = f2bf(v * SCALE);
                    else if (s == 1) sm[K_OFF + row * QK_STR + d] = f2bf(v);
                    else             sm[VT_OFF + d * VT_STR + row] = f2bf(v);
                }
            }
        }
        __syncthreads();

        f32x4 sacc[9];
        {
            bf16x8 a = *(const bf16x8*)&sm[Q_OFF + (wv * 16 + l15) * QK_STR + lq * 8];
#pragma unroll
            for (int nt = 0; nt < 9; ++nt) {
                bf16x8 bb = *(const bf16x8*)&sm[K_OFF + (nt * 16 + l15) * QK_STR + lq * 8];
                sacc[nt] = __builtin_amdgcn_mfma_f32_16x16x32_bf16(a, bb, fzero, 0, 0, 0);
            }
#pragma unroll
            for (int nt = 0; nt < 9; ++nt)
#pragma unroll
                for (int r = 0; r < 4; ++r) sacc[nt][r] += bsv[nt][r];
#pragma unroll
            for (int r = 0; r < 4; ++r) {
                float m = -1e30f;
                for (int nt = 0; nt < 9; ++nt) m = fmaxf(m, sacc[nt][r]);
                for (int d = 1; d < 16; d <<= 1) m = fmaxf(m, __shfl_xor(m, d, 64));
                float s = 0.f;
                for (int nt = 0; nt < 9; ++nt) {
                    float e = __expf(sacc[nt][r] - m);
                    sacc[nt][r] = e; s += e;
                }
                for (int d = 1; d < 16; d <<= 1) s += __shfl_xor(s, d, 64);
                float inv = 1.0f / s;
                for (int nt = 0; nt < 9; ++nt) sacc[nt][r] *= inv;
            }
        }

#pragma unroll
        for (int r = 0; r < 4; ++r) {
            int row = wv * 16 + lq * 4 + r;
#pragma unroll
            for (int nt = 0; nt < 9; ++nt)
                sm[P_OFF + row * P_STR + nt * 16 + l15] = f2bf(sacc[nt][r]);
            sm[P_OFF + row * P_STR + 144 + l15] = 0;
        }
        __syncthreads();

        f32x4 pv[2] = {fzero, fzero};
#pragma unroll
        for (int kt = 0; kt < 5; ++kt) {
            bf16x8 a = *(const bf16x8*)&sm[P_OFF + (wv * 16 + l15) * P_STR + kt * 32 + lq * 8];
#pragma unroll
            for (int dt = 0; dt < 2; ++dt) {
                bf16x8 bb = *(const bf16x8*)&sm[VT_OFF + (dt * 16 + l15) * VT_STR + kt * 32 + lq * 8];
                pv[dt] = __builtin_amdgcn_mfma_f32_16x16x32_bf16(a, bb, pv[dt], 0, 0, 0);
            }
        }

#pragma unroll
        for (int dt = 0; dt < 2; ++dt)
#pragma unroll
            for (int r = 0; r < 4; ++r) {
                int row = wv * 16 + lq * 4 + r;
                sm[OA_OFF + row * OA_STR + hoff + dt * 16 + l15] = f2bf(pv[dt][r]);
            }
        __syncthreads();
    }

    f32x4 oacc[12];
    for (int nt = 0; nt < 12; ++nt) oacc[nt] = fzero;
    {
        bf16x8 a[6];
#pragma unroll
        for (int kt = 0; kt < 6; ++kt)
            a[kt] = *(const bf16x8*)&sm[OA_OFF + (wv * 16 + l15) * OA_STR + kt * 32 + lq * 8];
#pragma unroll
        for (int kt = 0; kt < 6; ++kt) {
#pragma unroll
            for (int nt = 0; nt < 12; ++nt) {
                bf16x8 bb = FASTW
                    ? *(const bf16x8*)&projw_c[(size_t)(nt * 16 + l15) * CDIM + kt * 32 + lq * 8]
                    : ld_frag(proj_w, (size_t)(nt * 16 + l15) * CDIM + kt * 32 + lq * 8, fm);
                oacc[nt] = __builtin_amdgcn_mfma_f32_16x16x32_bf16(a[kt], bb, oacc[nt], 0, 0, 0);
            }
        }
    }

    const size_t obase = (size_t)bwlin * (NTOK * CDIM);
#pragma unroll
    for (int nt = 0; nt < 12; ++nt) {
        int col = nt * 16 + l15;
        float pb = FASTW ? bf2f(projb_c[col]) : ld_s(proj_b, col, fm);
#pragma unroll
        for (int r = 0; r < 4; ++r) {
            int row = wv * 16 + lq * 4 + r;
            st_s(out, obase + row * CDIM + col, oacc[nt][r] + pb, fm);
        }
    }
}

extern "C" void kernel_launch(void* const* d_in, const int* in_sizes, int n_in,
                              void* d_out, int out_size, void* d_ws, size_t ws_size,
                              hipStream_t stream) {
    const void* x          = d_in[0];
    const void* qkv_w      = d_in[1];
    const void* qkv_b      = d_in[2];
    const void* proj_w     = d_in[3];
    const void* proj_b     = d_in[4];
    const void* bias_table = d_in[5];
    const int*  pos_index  = (const int*)d_in[6];

    // ws layout: [16B flag][bias_g 15.93MB][qkvw 216KB][projw 72KB][qkvb][projb][o_ws 101MB]
    int*  mode_flag = (int*)d_ws;
    char* p         = (char*)d_ws + 16;
    const size_t biasg_bytes = (size_t)NWIN * NHEADS * NTOK * NTOK * sizeof(u16);
    u16* bias_g = (u16*)p;            p += biasg_bytes;
    u16* qkvw_c = (u16*)p;            p += (size_t)3 * CDIM * CDIM * sizeof(u16);
    u16* projw_c = (u16*)p;           p += (size_t)CDIM * CDIM * sizeof(u16);
    u16* qkvb_c = (u16*)p;            p += 3 * CDIM * sizeof(u16);
    u16* projb_c = (u16*)p;           p += CDIM * sizeof(u16);
    const size_t need_w = (size_t)(p - (char*)d_ws);
    u16* o_ws = (u16*)p;              p += (size_t)NBLK * NTOK * CDIM * sizeof(u16);
    const size_t need_split = (size_t)(p - (char*)d_ws);
    const size_t need_biasg = 16 + biasg_bytes;

    int use_bias_g = (ws_size >= need_biasg) ? 1 : 0;
    int use_w      = (ws_size >= need_w) ? 1 : 0;
    int use_split  = (ws_size >= need_split) ? 1 : 0;

    detect_mode<<<dim3(1), dim3(256), 0, stream>>>((const u16*)qkv_w, mode_flag);
    if (use_bias_g)
        bias_gather2<<<dim3(NWIN), dim3(256), 0, stream>>>(
            bias_table, pos_index, bias_g, mode_flag);
    if (use_w)
        wconv<<<dim3(192), dim3(256), 0, stream>>>(
            qkv_w, qkv_b, proj_w, proj_b, qkvw_c, projw_c, qkvb_c, projb_c, mode_flag);

    if (use_split) {
        attn_qkv<<<dim3(NBLK), dim3(512), 0, stream>>>(
            x, qkvw_c, qkvb_c, bias_g, o_ws, mode_flag);
        proj_gemm<<<dim3(NBLK * NTOK / 64), dim3(256), 0, stream>>>(
            o_ws, projw_c, projb_c, d_out, mode_flag);
    } else if (use_w) {
        earth_attn_fused<1><<<dim3(NBLK), dim3(576), 0, stream>>>(
            x, qkv_w, qkv_b, proj_w, proj_b, bias_table, pos_index,
            qkvw_c, projw_c, qkvb_c, projb_c, bias_g, 1, d_out, mode_flag);
    } else {
        earth_attn_fused<0><<<dim3(NBLK), dim3(576), 0, stream>>>(
            x, qkv_w, qkv_b, proj_w, proj_b, bias_table, pos_index,
            qkvw_c, projw_c, qkvb_c, projb_c, bias_g, use_bias_g, d_out, mode_flag);
    }
}

// Round 4
// 851.266 us; speedup vs baseline: 1.8317x; 1.8317x over previous
//
#include <hip/hip_runtime.h>

typedef unsigned short u16;
typedef unsigned int u32;

#define NTOK 144
#define CDIM 192
#define NHEADS 6
#define HDIM 32
#define NWIN 64
#define NB 30
#define NBLK (NB * NWIN)
#define TABLE_N 3312
#define SCALE 0.17677669529663687f

typedef __bf16 bf16x8 __attribute__((ext_vector_type(8)));
typedef u16 u16x8 __attribute__((ext_vector_type(8)));
typedef u16 u16x4 __attribute__((ext_vector_type(4)));
typedef float f32x4 __attribute__((ext_vector_type(4)));

__device__ __forceinline__ float bf2f(u16 u) {
    union { u32 i; float f; } v; v.i = ((u32)u) << 16; return v.f;
}
__device__ __forceinline__ u16 f2bf(float f) {
    union { float f; u32 i; } v; v.f = f;
    u32 r = v.i + 0x7FFFu + ((v.i >> 16) & 1u);   // RNE
    return (u16)(r >> 16);
}

// -------- dtype-robust accessors (fm==1: raw buffers are fp32) --------
__device__ __forceinline__ bf16x8 ld_frag(const void* base, size_t idx, int fm) {
    if (!fm) return *(const bf16x8*)((const u16*)base + idx);
    const float* pf = (const float*)base;
    u16x8 t;
#pragma unroll
    for (int j = 0; j < 8; ++j) t[j] = f2bf(pf[idx + j]);
    union { u16x8 u; bf16x8 b; } cv; cv.u = t; return cv.b;
}
__device__ __forceinline__ float ld_s(const void* base, size_t idx, int fm) {
    return fm ? ((const float*)base)[idx] : bf2f(((const u16*)base)[idx]);
}
__device__ __forceinline__ void st_s(void* base, size_t idx, float v, int fm) {
    if (fm) ((float*)base)[idx] = v; else ((u16*)base)[idx] = f2bf(v);
}
__device__ __forceinline__ bf16x8 zero_frag() {
    union { u16x8 u; bf16x8 b; } cv;
#pragma unroll
    for (int j = 0; j < 8; ++j) cv.u[j] = 0;
    return cv.b;
}
// x A-fragment loader (16B worth of bf16; converts when fm)
__device__ __forceinline__ bf16x8 ld_x_frag(const void* x, size_t rowbase, int off, int fm) {
    if (!fm) return *(const bf16x8*)((const u16*)x + rowbase + off);
    const float* xs = (const float*)x + rowbase + off;
    const float4 a0 = *(const float4*)xs;
    const float4 a1 = *(const float4*)(xs + 4);
    union { u16x8 u; bf16x8 b; } cv;
    cv.u[0] = f2bf(a0.x); cv.u[1] = f2bf(a0.y); cv.u[2] = f2bf(a0.z); cv.u[3] = f2bf(a0.w);
    cv.u[4] = f2bf(a1.x); cv.u[5] = f2bf(a1.y); cv.u[6] = f2bf(a1.z); cv.u[7] = f2bf(a1.w);
    return cv.b;
}

// -------- detector: bf16 vs fp32 input encoding --------
__global__ void detect_mode(const u16* __restrict__ w, int* __restrict__ flag) {
    __shared__ int cnt;
    if (threadIdx.x == 0) cnt = 0;
    __syncthreads();
    int h = 0;
    for (int i = threadIdx.x; i < 4096; i += 256) {
        int e = (w[i] >> 7) & 0xFF;
        if (e >= 0x8E) h++;
    }
    atomicAdd(&cnt, h);
    __syncthreads();
    if (threadIdx.x == 0) flag[0] = (cnt > 64) ? 1 : 0;
}

// -------- prologue: bias in MFMA FRAGMENT layout --------
// bias_f[w][h][T(9)][nt(9)][lane(64)][r(4)] bf16 : per (T,nt), lane reads its 4
// C-frag bias values as ONE contiguous 8B load (vs 36 scattered ushort gathers).
// One block per (w,h): stage table[:, w, h] column (3312 u16) in LDS first.
__global__ void bias_gather3(const void* __restrict__ table, const int* __restrict__ pos,
                             u16* __restrict__ bias_f, const int* __restrict__ mode) {
    __shared__ u16 smT[TABLE_N];
    const int fm = mode[0];
    const int w = blockIdx.x / NHEADS, h = blockIdx.x % NHEADS;
    for (int t = threadIdx.x; t < TABLE_N; t += 256) {
        size_t j = (size_t)t * (NWIN * NHEADS) + w * NHEADS + h;
        smT[t] = fm ? f2bf(((const float*)table)[j]) : ((const u16*)table)[j];
    }
    __syncthreads();
    u16* o = bias_f + (size_t)(w * NHEADS + h) * (81 * 256);
    for (int i = threadIdx.x; i < 81 * 256; i += 256) {
        int T = i / 2304, rem2 = i % 2304;
        int nt = rem2 >> 8, lane = (rem2 >> 2) & 63, r = rem2 & 3;
        int row = T * 16 + (lane >> 4) * 4 + r;
        int col = nt * 16 + (lane & 15);
        o[i] = smT[pos[row * NTOK + col]];
    }
}

// -------- prologue: canonical bf16 weights in workspace (one-time) --------
__global__ void wconv(const void* __restrict__ qkv_w, const void* __restrict__ qkv_b,
                      const void* __restrict__ proj_w, const void* __restrict__ proj_b,
                      u16* __restrict__ qkvw_c, u16* __restrict__ projw_c,
                      u16* __restrict__ qkvb_c, u16* __restrict__ projb_c,
                      const int* __restrict__ mode) {
    const int fm = mode[0];
    const int gid = blockIdx.x * blockDim.x + threadIdx.x;
    const int np  = gridDim.x * blockDim.x;
    const int NQW = 3 * CDIM * CDIM, NPW = CDIM * CDIM;
    if (fm) {
        const float* a = (const float*)qkv_w;
        const float* b = (const float*)proj_w;
        const float* c = (const float*)qkv_b;
        const float* d = (const float*)proj_b;
        for (int i = gid; i < NQW; i += np) qkvw_c[i] = f2bf(a[i]);
        for (int i = gid; i < NPW; i += np) projw_c[i] = f2bf(b[i]);
        for (int i = gid; i < 3 * CDIM; i += np) qkvb_c[i] = f2bf(c[i]);
        for (int i = gid; i < CDIM; i += np) projb_c[i] = f2bf(d[i]);
    } else {
        const u16* a = (const u16*)qkv_w;
        const u16* b = (const u16*)proj_w;
        const u16* c = (const u16*)qkv_b;
        const u16* d = (const u16*)proj_b;
        for (int i = gid; i < NQW; i += np) qkvw_c[i] = a[i];
        for (int i = gid; i < NPW; i += np) projw_c[i] = b[i];
        for (int i = gid; i < 3 * CDIM; i += np) qkvb_c[i] = c[i];
        for (int i = gid; i < CDIM; i += np) projb_c[i] = d[i];
    }
}

// =================== split-path kernel 1: fused qkv + attention ===================
// 576 thr (9 waves), 1 M-tile per wave (no imbalance), target 2 blocks/CU (VGPR<=64).
// W head-slice staged in LDS (overlaying P: W live stage->B1, P live B1..B3).
// Bias via fragment-layout coalesced 8B loads. O written head-major (full lines).
// LDS (u16): Q[144][40]@0, K[144][40]@5760, P/W[144][152]@11520, vT[32][152]@33408
// Strides: 40u16=20dw==20 mod 32; 152u16=76dw==12 mod 32; W staged at stride 200
// (100dw==4 mod 32) -- all ~2-way on 16-row b128 reads (free).
#define AQ_OFF  0
#define AK_OFF  5760
#define AQK_STR 40
#define APB_OFF 11520
#define AP_STR  152
#define AW_STR  200
#define AVT_OFF 33408
#define AVT_STR 152
#define ASM_TOT 38272    // u16 units = 76,544 B  (x2 blocks = 153 KB <= 160 KB)

__global__ __launch_bounds__(576, 8)
void attn_qkv(const void* __restrict__ x,
              const u16* __restrict__ qkvw_c, const u16* __restrict__ qkvb_c,
              const u16* __restrict__ bias_f, u16* __restrict__ o_ws,
              const int* __restrict__ mode) {
    __shared__ __align__(16) u16 sm[ASM_TOT];

    const int fm   = mode[0];
    const int tid  = threadIdx.x;
    const int wv   = tid >> 6;       // 0..8  (M-tile owner)
    const int lane = tid & 63;
    const int l15  = lane & 15;
    const int lq   = lane >> 4;      // 0..3

    // XCD-chunked swizzle + window-major remap (bias_f/weights L2-local per XCD)
    const int blk   = blockIdx.x;                       // 0..1919
    const int virt  = (blk & 7) * (NBLK / 8) + (blk >> 3);
    const int w     = virt / NB;                        // 0..63
    const int bwlin = (virt % NB) * NWIN + w;           // linear (b,w) index into x/o_ws

    const size_t xrow = ((size_t)bwlin * NTOK + wv * 16 + l15) * CDIM;
    const f32x4 fzero = {0.f, 0.f, 0.f, 0.f};

    for (int h = 0; h < NHEADS; ++h) {
        const int hoff = h * HDIM;

        // ---- stage W head-slice (96x192) into P-region as [96][200] bf16 ----
        // slice row r <-> qkvw row (r>>5)*CDIM + hoff + (r&31); B-frag row for
        // output col c is simply c (c = s*32+d = nt*16+l15).
        for (int i = tid; i < 96 * CDIM / 8; i += 576) {      // 2304 = 4*576
            int r = i / 24, c8 = (i % 24) * 8;
            int grow = (r >> 5) * CDIM + hoff + (r & 31);
            *(uint4*)&sm[APB_OFF + r * AW_STR + c8] =
                *(const uint4*)(qkvw_c + (size_t)grow * CDIM + c8);
        }
        __syncthreads();                              // Bs (W staged; prev P reads done at B3)

        // ---- t1: qkv_h = x @ Wh^T (M=144,N=96,K=192); A global, B from LDS ----
        {
            f32x4 acc[6];
#pragma unroll
            for (int nt = 0; nt < 6; ++nt) acc[nt] = fzero;
#pragma unroll
            for (int kt = 0; kt < 6; ++kt) {
                bf16x8 xf = ld_x_frag(x, xrow, kt * 32 + lq * 8, fm);
#pragma unroll
                for (int nt = 0; nt < 6; ++nt) {
                    bf16x8 bb = *(const bf16x8*)&sm[APB_OFF + (nt * 16 + l15) * AW_STR + kt * 32 + lq * 8];
                    acc[nt] = __builtin_amdgcn_mfma_f32_16x16x32_bf16(xf, bb, acc[nt], 0, 0, 0);
                }
            }
            // scatter q (scaled) / k / v^T as bf16
#pragma unroll
            for (int nt = 0; nt < 6; ++nt) {
                int col = nt * 16 + l15;         // 0..95
                int s = col >> 5, d = col & 31;
                float bias = bf2f(qkvb_c[s * CDIM + hoff + d]);
#pragma unroll
                for (int r = 0; r < 4; ++r) {
                    int row = wv * 16 + lq * 4 + r;
                    float v = acc[nt][r] + bias;
                    if (s == 0)      sm[AQ_OFF + row * AQK_STR + d] = f2bf(v * SCALE);
                    else if (s == 1) sm[AK_OFF + row * AQK_STR + d] = f2bf(v);
                    else             sm[AVT_OFF + d * AVT_STR + row] = f2bf(v);
                }
            }
        }
        __syncthreads();                              // B1 (q/k/vT visible; W reads done)

        // ---- t2: S = q@k^T + bias(frag-coalesced); softmax in regs ----
        f32x4 sacc[9];
        {
            bf16x8 a = *(const bf16x8*)&sm[AQ_OFF + (wv * 16 + l15) * AQK_STR + lq * 8];
#pragma unroll
            for (int nt = 0; nt < 9; ++nt) {
                bf16x8 bb = *(const bf16x8*)&sm[AK_OFF + (nt * 16 + l15) * AQK_STR + lq * 8];
                sacc[nt] = __builtin_amdgcn_mfma_f32_16x16x32_bf16(a, bb, fzero, 0, 0, 0);
            }
            const u16* bf = bias_f + ((size_t)(w * NHEADS + h) * 81 + wv * 9) * 256;
#pragma unroll
            for (int nt = 0; nt < 9; ++nt) {
                u16x4 pk = *(const u16x4*)&bf[nt * 256 + (lane << 2)];
#pragma unroll
                for (int r = 0; r < 4; ++r) sacc[nt][r] += bf2f(pk[r]);
            }
#pragma unroll
            for (int r = 0; r < 4; ++r) {
                float m = -1e30f;
                for (int nt = 0; nt < 9; ++nt) m = fmaxf(m, sacc[nt][r]);
                for (int d = 1; d < 16; d <<= 1) m = fmaxf(m, __shfl_xor(m, d, 64));
                float s = 0.f;
                for (int nt = 0; nt < 9; ++nt) {
                    float e = __expf(sacc[nt][r] - m);
                    sacc[nt][r] = e; s += e;
                }
                for (int d = 1; d < 16; d <<= 1) s += __shfl_xor(s, d, 64);
                float inv = 1.0f / s;
                for (int nt = 0; nt < 9; ++nt) sacc[nt][r] *= inv;
            }
        }

        // ---- P write (overwrites W region; safe: W readers fenced at B1) ----
#pragma unroll
        for (int r = 0; r < 4; ++r) {
            int row = wv * 16 + lq * 4 + r;
#pragma unroll
            for (int nt = 0; nt < 9; ++nt)
                sm[APB_OFF + row * AP_STR + nt * 16 + l15] = f2bf(sacc[nt][r]);
        }
        __syncthreads();                              // B2 (P ready)

        // ---- t3: O_h = P @ v (K=144 via masked kt=4); O -> global head-major ----
        {
            f32x4 pv[2] = {fzero, fzero};
#pragma unroll
            for (int kt = 0; kt < 4; ++kt) {
                bf16x8 a = *(const bf16x8*)&sm[APB_OFF + (wv * 16 + l15) * AP_STR + kt * 32 + lq * 8];
#pragma unroll
                for (int dt = 0; dt < 2; ++dt) {
                    bf16x8 bb = *(const bf16x8*)&sm[AVT_OFF + (dt * 16 + l15) * AVT_STR + kt * 32 + lq * 8];
                    pv[dt] = __builtin_amdgcn_mfma_f32_16x16x32_bf16(a, bb, pv[dt], 0, 0, 0);
                }
            }
            // kt=4: real k = 128..143 (lq 0,1); lq 2,3 masked with zero A-frag
            bf16x8 a4 = zero_frag();
            if (lq < 2)
                a4 = *(const bf16x8*)&sm[APB_OFF + (wv * 16 + l15) * AP_STR + 128 + lq * 8];
#pragma unroll
            for (int dt = 0; dt < 2; ++dt) {
                bf16x8 bb = *(const bf16x8*)&sm[AVT_OFF + (dt * 16 + l15) * AVT_STR + 128 + (lq & 1) * 8];
                pv[dt] = __builtin_amdgcn_mfma_f32_16x16x32_bf16(a4, bb, pv[dt], 0, 0, 0);
            }
            // head-major o_ws[h][bwlin][144][32]: full-line coalesced writes
            u16* op = o_ws + (((size_t)h * NBLK + bwlin) * NTOK + wv * 16 + lq * 4) * HDIM;
#pragma unroll
            for (int dt = 0; dt < 2; ++dt)
#pragma unroll
                for (int r = 0; r < 4; ++r)
                    op[r * HDIM + dt * 16 + l15] = f2bf(pv[dt][r]);
        }
        __syncthreads();                              // B3 (P/vT/Q/K dead; next head safe)
    }
}

// =================== split-path kernel 2: output projection GEMM ===================
// out = O @ proj_w^T + b. proj_w staged ONCE per block in LDS [192][200];
// 512 thr (8 waves), 1 tile/wave, grid 2160 -> W L2 traffic 5GB -> 166MB.
#define PW_STR 200
__global__ __launch_bounds__(512, 4)
void proj_gemm(const u16* __restrict__ o_ws, const u16* __restrict__ projw_c,
               const u16* __restrict__ projb_c, void* __restrict__ out,
               const int* __restrict__ mode) {
    __shared__ __align__(16) u16 smW[CDIM * PW_STR];   // 76,800 B
    const int fm   = mode[0];
    const int tid  = threadIdx.x;
    const int wv   = tid >> 6;
    const int lane = tid & 63;
    const int l15  = lane & 15;
    const int lq   = lane >> 4;

    // stage proj_w [192][192] -> LDS stride 200
    for (int i = tid; i < CDIM * CDIM / 8; i += 512) {   // 4608 = 9*512
        int r = i / 24, c8 = (i % 24) * 8;
        *(uint4*)&smW[r * PW_STR + c8] = *(const uint4*)(projw_c + (size_t)r * CDIM + c8);
    }
    __syncthreads();

    const int tile = blockIdx.x * 8 + wv;             // 0..17279
    const int win  = tile / 9;
    const int trow = (tile % 9) * 16;
    const f32x4 fzero = {0.f, 0.f, 0.f, 0.f};

    // A-fragments: K=192 spans 6 heads x 32 in o_ws head-major layout
    bf16x8 a[6];
#pragma unroll
    for (int kt = 0; kt < 6; ++kt)
        a[kt] = *(const bf16x8*)&o_ws[((size_t)kt * NBLK + win) * (NTOK * HDIM)
                                      + (trow + l15) * HDIM + lq * 8];

    f32x4 acc[12];
#pragma unroll
    for (int nt = 0; nt < 12; ++nt) acc[nt] = fzero;
#pragma unroll
    for (int kt = 0; kt < 6; ++kt) {
#pragma unroll
        for (int nt = 0; nt < 12; ++nt) {
            bf16x8 bb = *(const bf16x8*)&smW[(nt * 16 + l15) * PW_STR + kt * 32 + lq * 8];
            acc[nt] = __builtin_amdgcn_mfma_f32_16x16x32_bf16(a[kt], bb, acc[nt], 0, 0, 0);
        }
    }
    const size_t rb = (size_t)win * (NTOK * CDIM) + (size_t)trow * CDIM;
#pragma unroll
    for (int nt = 0; nt < 12; ++nt) {
        int col = nt * 16 + l15;
        float pb = bf2f(projb_c[col]);
#pragma unroll
        for (int r = 0; r < 4; ++r)
            st_s(out, rb + (lq * 4 + r) * CDIM + col, acc[nt][r] + pb, fm);
    }
}

// =================== fallback: monolithic fused kernel (small-ws path) ===================
#define Q_OFF  0
#define K_OFF  5760
#define QK_STR 40
#define P_OFF  11520
#define P_STR  168
#define VT_OFF 35712
#define VT_STR 168
#define OA_OFF 41088
#define OA_STR 200
#define SM_TOT 69888

template<int FASTW>
__global__ __launch_bounds__(576, 3)
void earth_attn_fused(const void* __restrict__ x, const void* __restrict__ qkv_w,
                const void* __restrict__ qkv_b, const void* __restrict__ proj_w,
                const void* __restrict__ proj_b, const void* __restrict__ bias_table,
                const int* __restrict__ pos_index,
                const u16* __restrict__ qkvw_c, const u16* __restrict__ projw_c,
                const u16* __restrict__ qkvb_c, const u16* __restrict__ projb_c,
                const u16* __restrict__ bias_f, int use_bias_f,
                void* __restrict__ out, const int* __restrict__ mode) {
    __shared__ __align__(16) u16 sm[SM_TOT];

    const int fm   = mode[0];
    const int tid  = threadIdx.x;
    const int wv   = tid >> 6;
    const int lane = tid & 63;
    const int l15  = lane & 15;
    const int lq   = lane >> 4;

    const int blk   = blockIdx.x;
    const int virt  = (blk & 7) * (NBLK / 8) + (blk >> 3);
    const int w     = virt / NB;
    const int bwlin = (virt % NB) * NWIN + w;

    {
        uint4 z; z.x = z.y = z.z = z.w = 0u;
        for (int i = tid; i < (32 * VT_STR) / 8; i += 576) *(uint4*)&sm[VT_OFF + i * 8] = z;
    }

    bf16x8 xfrag[6];
    {
        const size_t xrow = ((size_t)bwlin * NTOK + wv * 16 + l15) * CDIM;
#pragma unroll
        for (int kt = 0; kt < 6; ++kt) xfrag[kt] = ld_x_frag(x, xrow, kt * 32 + lq * 8, fm);
    }
    __syncthreads();

    const f32x4 fzero = {0.f, 0.f, 0.f, 0.f};

    for (int h = 0; h < NHEADS; ++h) {
        const int hoff = h * HDIM;

        float bsv[9][4];
        if (FASTW || use_bias_f) {
            const u16* bf = bias_f + ((size_t)(w * NHEADS + h) * 81 + wv * 9) * 256;
#pragma unroll
            for (int nt = 0; nt < 9; ++nt) {
                u16x4 pk = *(const u16x4*)&bf[nt * 256 + (lane << 2)];
#pragma unroll
                for (int r = 0; r < 4; ++r) bsv[nt][r] = bf2f(pk[r]);
            }
        } else {
#pragma unroll
            for (int nt = 0; nt < 9; ++nt) {
                int col = nt * 16 + l15;
#pragma unroll
                for (int r = 0; r < 4; ++r) {
                    int idx = pos_index[(wv * 16 + lq * 4 + r) * NTOK + col];
                    bsv[nt][r] = ld_s(bias_table, ((size_t)idx * NWIN + w) * NHEADS + h, fm);
                }
            }
        }

        {
            f32x4 acc[6];
            for (int nt = 0; nt < 6; ++nt) acc[nt] = fzero;
            int wrow[6];
#pragma unroll
            for (int nt = 0; nt < 6; ++nt) {
                int c = nt * 16 + l15, s = c >> 5, d = c & 31;
                wrow[nt] = (s * CDIM + hoff + d) * CDIM;
            }
#pragma unroll
            for (int kt = 0; kt < 6; ++kt) {
#pragma unroll
                for (int nt = 0; nt < 6; ++nt) {
                    bf16x8 bb = FASTW
                        ? *(const bf16x8*)&qkvw_c[(size_t)wrow[nt] + kt * 32 + lq * 8]
                        : ld_frag(qkv_w, (size_t)wrow[nt] + kt * 32 + lq * 8, fm);
                    acc[nt] = __builtin_amdgcn_mfma_f32_16x16x32_bf16(xfrag[kt], bb, acc[nt], 0, 0, 0);
                }
            }
#pragma unroll
            for (int nt = 0; nt < 6; ++nt) {
                int col = nt * 16 + l15;
                int s = col >> 5, d = col & 31;
                float bias = FASTW ? bf2f(qkvb_c[s * CDIM + hoff + d])
                                   : ld_s(qkv_b, s * CDIM + hoff + d, fm);
#pragma unroll
                for (int r = 0; r < 4; ++r) {
                    int row = wv * 16 + lq * 4 + r;
                    float v = acc[nt][r] + bias;
                    if (s == 0)      sm[Q_OFF + row * QK_STR + d] = f2bf(v * SCALE);
                    else if (s == 1) sm[K_OFF + row * QK_STR + d] = f2bf(v);
                    else             sm[VT_OFF + d * VT_STR + row] = f2bf(v);
                }
            }
        }
        __syncthreads();

        f32x4 sacc[9];
        {
            bf16x8 a = *(const bf16x8*)&sm[Q_OFF + (wv * 16 + l15) * QK_STR + lq * 8];
#pragma unroll
            for (int nt = 0; nt < 9; ++nt) {
                bf16x8 bb = *(const bf16x8*)&sm[K_OFF + (nt * 16 + l15) * QK_STR + lq * 8];
                sacc[nt] = __builtin_amdgcn_mfma_f32_16x16x32_bf16(a, bb, fzero, 0, 0, 0);
            }
#pragma unroll
            for (int nt = 0; nt < 9; ++nt)
#pragma unroll
                for (int r = 0; r < 4; ++r) sacc[nt][r] += bsv[nt][r];
#pragma unroll
            for (int r = 0; r < 4; ++r) {
                float m = -1e30f;
                for (int nt = 0; nt < 9; ++nt) m = fmaxf(m, sacc[nt][r]);
                for (int d = 1; d < 16; d <<= 1) m = fmaxf(m, __shfl_xor(m, d, 64));
                float s = 0.f;
                for (int nt = 0; nt < 9; ++nt) {
                    float e = __expf(sacc[nt][r] - m);
                    sacc[nt][r] = e; s += e;
                }
                for (int d = 1; d < 16; d <<= 1) s += __shfl_xor(s, d, 64);
                float inv = 1.0f / s;
                for (int nt = 0; nt < 9; ++nt) sacc[nt][r] *= inv;
            }
        }

#pragma unroll
        for (int r = 0; r < 4; ++r) {
            int row = wv * 16 + lq * 4 + r;
#pragma unroll
            for (int nt = 0; nt < 9; ++nt)
                sm[P_OFF + row * P_STR + nt * 16 + l15] = f2bf(sacc[nt][r]);
            sm[P_OFF + row * P_STR + 144 + l15] = 0;
        }
        __syncthreads();

        f32x4 pv[2] = {fzero, fzero};
#pragma unroll
        for (int kt = 0; kt < 5; ++kt) {
            bf16x8 a = *(const bf16x8*)&sm[P_OFF + (wv * 16 + l15) * P_STR + kt * 32 + lq * 8];
#pragma unroll
            for (int dt = 0; dt < 2; ++dt) {
                bf16x8 bb = *(const bf16x8*)&sm[VT_OFF + (dt * 16 + l15) * VT_STR + kt * 32 + lq * 8];
                pv[dt] = __builtin_amdgcn_mfma_f32_16x16x32_bf16(a, bb, pv[dt], 0, 0, 0);
            }
        }

#pragma unroll
        for (int dt = 0; dt < 2; ++dt)
#pragma unroll
            for (int r = 0; r < 4; ++r) {
                int row = wv * 16 + lq * 4 + r;
                sm[OA_OFF + row * OA_STR + hoff + dt * 16 + l15] = f2bf(pv[dt][r]);
            }
        __syncthreads();
    }

    f32x4 oacc[12];
    for (int nt = 0; nt < 12; ++nt) oacc[nt] = fzero;
    {
        bf16x8 a[6];
#pragma unroll
        for (int kt = 0; kt < 6; ++kt)
            a[kt] = *(const bf16x8*)&sm[OA_OFF + (wv * 16 + l15) * OA_STR + kt * 32 + lq * 8];
#pragma unroll
        for (int kt = 0; kt < 6; ++kt) {
#pragma unroll
            for (int nt = 0; nt < 12; ++nt) {
                bf16x8 bb = FASTW
                    ? *(const bf16x8*)&projw_c[(size_t)(nt * 16 + l15) * CDIM + kt * 32 + lq * 8]
                    : ld_frag(proj_w, (size_t)(nt * 16 + l15) * CDIM + kt * 32 + lq * 8, fm);
                oacc[nt] = __builtin_amdgcn_mfma_f32_16x16x32_bf16(a[kt], bb, oacc[nt], 0, 0, 0);
            }
        }
    }

    const size_t obase = (size_t)bwlin * (NTOK * CDIM);
#pragma unroll
    for (int nt = 0; nt < 12; ++nt) {
        int col = nt * 16 + l15;
        float pb = FASTW ? bf2f(projb_c[col]) : ld_s(proj_b, col, fm);
#pragma unroll
        for (int r = 0; r < 4; ++r) {
            int row = wv * 16 + lq * 4 + r;
            st_s(out, obase + row * CDIM + col, oacc[nt][r] + pb, fm);
        }
    }
}

extern "C" void kernel_launch(void* const* d_in, const int* in_sizes, int n_in,
                              void* d_out, int out_size, void* d_ws, size_t ws_size,
                              hipStream_t stream) {
    const void* x          = d_in[0];
    const void* qkv_w      = d_in[1];
    const void* qkv_b      = d_in[2];
    const void* proj_w     = d_in[3];
    const void* proj_b     = d_in[4];
    const void* bias_table = d_in[5];
    const int*  pos_index  = (const int*)d_in[6];

    // ws layout: [16B flag][bias_f 15.93MB][qkvw 216KB][projw 72KB][qkvb][projb][o_ws 101MB]
    int*  mode_flag = (int*)d_ws;
    char* p         = (char*)d_ws + 16;
    const size_t biasf_bytes = (size_t)NWIN * NHEADS * 81 * 256 * sizeof(u16);
    u16* bias_f = (u16*)p;            p += biasf_bytes;
    u16* qkvw_c = (u16*)p;            p += (size_t)3 * CDIM * CDIM * sizeof(u16);
    u16* projw_c = (u16*)p;           p += (size_t)CDIM * CDIM * sizeof(u16);
    u16* qkvb_c = (u16*)p;            p += 3 * CDIM * sizeof(u16);
    u16* projb_c = (u16*)p;           p += CDIM * sizeof(u16);
    const size_t need_w = (size_t)(p - (char*)d_ws);
    u16* o_ws = (u16*)p;              p += (size_t)NHEADS * NBLK * NTOK * HDIM * sizeof(u16);
    const size_t need_split = (size_t)(p - (char*)d_ws);
    const size_t need_biasf = 16 + biasf_bytes;

    int use_bias_f = (ws_size >= need_biasf) ? 1 : 0;
    int use_w      = (ws_size >= need_w) ? 1 : 0;
    int use_split  = (ws_size >= need_split) ? 1 : 0;

    detect_mode<<<dim3(1), dim3(256), 0, stream>>>((const u16*)qkv_w, mode_flag);
    if (use_bias_f)
        bias_gather3<<<dim3(NWIN * NHEADS), dim3(256), 0, stream>>>(
            bias_table, pos_index, bias_f, mode_flag);
    if (use_w)
        wconv<<<dim3(192), dim3(256), 0, stream>>>(
            qkv_w, qkv_b, proj_w, proj_b, qkvw_c, projw_c, qkvb_c, projb_c, mode_flag);

    if (use_split) {
        attn_qkv<<<dim3(NBLK), dim3(576), 0, stream>>>(
            x, qkvw_c, qkvb_c, bias_f, o_ws, mode_flag);
        proj_gemm<<<dim3(NBLK * 9 / 8), dim3(512), 0, stream>>>(
            o_ws, projw_c, projb_c, d_out, mode_flag);
    } else if (use_w) {
        earth_attn_fused<1><<<dim3(NBLK), dim3(576), 0, stream>>>(
            x, qkv_w, qkv_b, proj_w, proj_b, bias_table, pos_index,
            qkvw_c, projw_c, qkvb_c, projb_c, bias_f, 1, d_out, mode_flag);
    } else {
        earth_attn_fused<0><<<dim3(NBLK), dim3(576), 0, stream>>>(
            x, qkv_w, qkv_b, proj_w, proj_b, bias_table, pos_index,
            qkvw_c, projw_c, qkvb_c, projb_c, bias_f, use_bias_f, d_out, mode_flag);
    }
}